// Round 5
// baseline (203.692 us; speedup 1.0000x reference)
//
#include <hip/hip_runtime.h>

// VisitEncoder: out[v,:] = mean over valid codes j of logmap0(emb[ids[v,j]]), c=1.
//
// R14: phase-locked 2-pass windowed gather (clean test of the L2-capacity
// theory). R12's temporal windowing was null because waves mixed phases
// chip-wide (4096 blocks, 2 dispatch rounds); R13's dim-half split regressed
// (unverified bid%8->XCD mapping + 2x request count + 2x ids reads). Fix:
//   * K3 is a PERSISTENT kernel: exactly 1024 blocks x 256 thr,
//     __launch_bounds__(256,4) (VGPR<=128 -> 16 waves/CU -> all 4 blocks/CU
//     co-resident from t~0). Every wave runs pass A (rows [0,C/2)) then
//     pass B (rows [C/2,C)) in the same order -> during each phase every
//     XCD's gather working set is one 3.2MB half < 4MB L2.
//   * 64B rows kept (R13's 32B half-rows doubled request count); ids read
//     once; out-of-window / padded ids gather the L1-hot zero row C
//     (bit-identical sums, proven in R12).
//   * each wave: 4 visit-groups x 4 visits (16 visits); __syncthreads()
//     between passes holds block-level phase alignment.
//   * R11's verified 16-lane/visit reduce + epilogue reused per group.
// Math bit-identical to R9..R13 (same u8 table, exact packed-u16 sums,
// same fbias/qinv epilogue). Expected absmax 1.144409e-05.

#define LCODES 48
#define DIM 64
#define K3_BLOCKS 1024
#define CHUNKS (K3_BLOCKS * 4)   // one chunk = 4 visits handled by one wave
#define NG 4                     // visit-groups per wave (16 visits/wave)

typedef float vf4 __attribute__((ext_vector_type(4)));

// ---------- K1: block-max of |emb| (positive-float bits are monotone) ----------
__global__ __launch_bounds__(256)
void amax_kernel(const float* __restrict__ emb, unsigned* __restrict__ bmax,
                 long n4) {
    const uint4* __restrict__ u4 = reinterpret_cast<const uint4*>(emb);
    const long T = (long)gridDim.x * 256;
    unsigned m = 0;
    for (long i = (long)blockIdx.x * 256 + threadIdx.x; i < n4; i += 2 * T) {
        const uint4 a = u4[i];
        m = max(m, a.x & 0x7fffffffu);
        m = max(m, a.y & 0x7fffffffu);
        m = max(m, a.z & 0x7fffffffu);
        m = max(m, a.w & 0x7fffffffu);
        if (i + T < n4) {
            const uint4 b = u4[i + T];
            m = max(m, b.x & 0x7fffffffu);
            m = max(m, b.y & 0x7fffffffu);
            m = max(m, b.z & 0x7fffffffu);
            m = max(m, b.w & 0x7fffffffu);
        }
    }
    #pragma unroll
    for (int d = 1; d <= 32; d <<= 1)
        m = max(m, (unsigned)__shfl_xor((int)m, d, 64));
    __shared__ unsigned sm[4];
    if ((threadIdx.x & 63) == 0) sm[threadIdx.x >> 6] = m;
    __syncthreads();
    if (threadIdx.x == 0)
        bmax[blockIdx.x] = max(max(sm[0], sm[1]), max(sm[2], sm[3]));
}

__device__ __forceinline__ float global_amax1024(const unsigned* __restrict__ bmax) {
    const int lane = threadIdx.x & 63;
    unsigned m = 0;
    #pragma unroll
    for (int k = 0; k < 16; ++k)
        m = max(m, bmax[lane + 64 * k]);
    #pragma unroll
    for (int d = 1; d <= 32; d <<= 1)
        m = max(m, (unsigned)__shfl_xor((int)m, d, 64));
    return __uint_as_float(m);
}

// ---------- K2: fp32 emb -> uint8 table (C+1 rows x 64B, row C = zeros) ----------
__global__ __launch_bounds__(256)
void build_i8_kernel(const float* __restrict__ emb,
                     const unsigned* __restrict__ bmax,
                     unsigned char* __restrict__ tab,
                     float* __restrict__ qsout, int C) {
    const float amax = global_amax1024(bmax);
    // 1.0006 bounds the artanh scale factor (ss <= 64*amax^2 -> scale <= 1.00056)
    const float qs   = amax * (1.0006f / 127.f);
    const float invq = (amax > 0.f) ? (127.f / (amax * 1.0006f)) : 0.f;
    if (blockIdx.x == 0 && threadIdx.x == 0) qsout[0] = qs;
    // zero-row for padded / out-of-window ids
    if (blockIdx.x == 0 && threadIdx.x < 16)
        reinterpret_cast<unsigned*>(tab + (size_t)C * DIM)[threadIdx.x] = 0u;

    const int tid  = threadIdx.x;
    const int lane = tid & 63;
    const int wave = tid >> 6;
    const int g = lane >> 3, s = lane & 7;
    const int r = blockIdx.x * 32 + wave * 8 + g;
    if (r >= C) return;

    const float4* __restrict__ emb4 = reinterpret_cast<const float4*>(emb);
    const float4 a = emb4[r * 16 + 2 * s];       // dims 8s..8s+3
    const float4 b = emb4[r * 16 + 2 * s + 1];   // dims 8s+4..8s+7

    float ss = a.x*a.x + a.y*a.y + a.z*a.z + a.w*a.w
             + b.x*b.x + b.y*b.y + b.z*b.z + b.w*b.w;
    ss += __shfl_xor(ss, 1, 64);
    ss += __shfl_xor(ss, 2, 64);
    ss += __shfl_xor(ss, 4, 64);

    float scale;
    if (__builtin_expect(ss > 0.04f, 0)) {
        // exact artanh path (never taken for this data; correctness guard)
        const float norm = fmaxf(sqrtf(ss), 1e-15f);
        const float arg  = fminf(norm, 1.f - 1e-7f);
        scale = 0.5f * logf((1.f + arg) / (1.f - arg)) / norm;
    } else {
        // artanh(z)/z = 1 + z^2/3 + z^4/5 + z^6/7,  z^2 = ss
        scale = 1.f + ss * (0.33333333333f + ss * (0.2f + ss * 0.14285714285f));
    }
    scale *= invq;   // fold quantization step into the tangent scale

    const float t[8] = { a.x*scale, a.y*scale, a.z*scale, a.w*scale,
                         b.x*scale, b.y*scale, b.z*scale, b.w*scale };
    unsigned u[8];
    #pragma unroll
    for (int k = 0; k < 8; ++k)
        u[k] = (unsigned)((int)rintf(t[k]) + 128);   // in [1,255]

    uint2 w;
    w.x = u[0] | (u[1] << 8) | (u[2] << 16) | (u[3] << 24);
    w.y = u[4] | (u[5] << 8) | (u[6] << 16) | (u[7] << 24);
    reinterpret_cast<uint2*>(tab)[r * 8 + s] = w;   // 64B/row, coalesced
}

// ---------- K3: persistent phase-locked 2-pass windowed gather-mean ----------
__global__ __launch_bounds__(256, 4)
void visit_gather_i8p_kernel(const int* __restrict__ ids,
                             const unsigned char* __restrict__ tab,
                             const float* __restrict__ qsp,
                             float* __restrict__ out, int N, int C) {
    const float qs = qsp[0];          // uniform scalar load, hot line

    const int tid   = threadIdx.x;
    const int lane  = tid & 63;
    const int wave  = tid >> 6;
    const int chunk = blockIdx.x * 4 + wave;   // 0..CHUNKS-1

    __shared__ int   sids[4][NG][4 * 50];   // stride 50: <=2-way bank alias (free)
    __shared__ float scnt[4][NG][4];

    // Prologue: load NG groups x 4 visits of ids (lanes 0..47), stash in LDS.
    // Same-wave producer/consumer: no barrier needed before first use.
    #pragma unroll
    for (int g = 0; g < NG; ++g) {
        const int v0 = (g * CHUNKS + chunk) * 4;
        int m0 = -1, m1 = -1, m2 = -1, m3 = -1;
        if (lane < LCODES) {
            const long b = (long)v0 * LCODES + lane;
            if (v0     < N) m0 = __builtin_nontemporal_load(&ids[b]);
            if (v0 + 1 < N) m1 = __builtin_nontemporal_load(&ids[b + LCODES]);
            if (v0 + 2 < N) m2 = __builtin_nontemporal_load(&ids[b + 2 * LCODES]);
            if (v0 + 3 < N) m3 = __builtin_nontemporal_load(&ids[b + 3 * LCODES]);
            sids[wave][g][lane]           = m0;
            sids[wave][g][50 + lane]      = m1;
            sids[wave][g][100 + lane]     = m2;
            sids[wave][g][150 + lane]     = m3;
        }
        const float c0 = (float)__popcll(__ballot(m0 >= 0));
        const float c1 = (float)__popcll(__ballot(m1 >= 0));
        const float c2 = (float)__popcll(__ballot(m2 >= 0));
        const float c3 = (float)__popcll(__ballot(m3 >= 0));
        if (lane == 0) {
            scnt[wave][g][0] = c0;  scnt[wave][g][1] = c1;
            scnt[wave][g][2] = c2;  scnt[wave][g][3] = c3;
        }
    }

    const int v = lane >> 4;          // visit within group
    const int gg = (lane >> 2) & 3;   // code-subgroup within iteration
    const int s = lane & 3;           // uint4 slot = dims [16s..16s+15]
    const uint4* __restrict__ tab4 = reinterpret_cast<const uint4*>(tab);

    // Packed accumulators per group: each u32 = two 16-bit sums (even/odd
    // bytes); word k covers dims 16s+4k+{0..3}. Each id hits its real row in
    // exactly one pass and the zero row in the other: 48*255 < 2^16, exact.
    unsigned aE[NG][4] = {{0}}, aO[NG][4] = {{0}};

    const int C2 = C >> 1;
    #pragma unroll
    for (int p = 0; p < 2; ++p) {
        const int lo = p ? C2 : 0;
        const int hi = p ? C  : C2;
        #pragma unroll
        for (int g = 0; g < NG; ++g) {
            const int* __restrict__ slid = &sids[wave][g][v * 50 + gg];
            #pragma unroll
            for (int it = 0; it < LCODES / 4; ++it) {
                const int id = slid[4 * it];
                const bool inw = (id >= lo) & (id < hi);  // pads never in window
                const unsigned base = ((unsigned)(inw ? id : C)) << 2;
                const uint4 w = tab4[base + s];   // live window: 3.2MB per XCD
                aE[g][0] +=  w.x       & 0x00ff00ffu;
                aO[g][0] += (w.x >> 8) & 0x00ff00ffu;
                aE[g][1] +=  w.y       & 0x00ff00ffu;
                aO[g][1] += (w.y >> 8) & 0x00ff00ffu;
                aE[g][2] +=  w.z       & 0x00ff00ffu;
                aO[g][2] += (w.z >> 8) & 0x00ff00ffu;
                aE[g][3] +=  w.w       & 0x00ff00ffu;
                aO[g][3] += (w.w >> 8) & 0x00ff00ffu;
            }
        }
        // Pin the pass boundary (no hoisting of pass-B loads into pass A)
        // and re-align the block's waves at the phase edge.
        __builtin_amdgcn_sched_barrier(0);
        __syncthreads();
    }

    // Per group: combine the 4 gg-subgroups (lane bits 2..3), then each lane
    // assembles and stores ONE float4 (R11's verified epilogue).
    #pragma unroll
    for (int g = 0; g < NG; ++g) {
        #pragma unroll
        for (int d = 4; d <= 8; d <<= 1) {
            #pragma unroll
            for (int k = 0; k < 4; ++k) {
                aE[g][k] += (unsigned)__shfl_xor((int)aE[g][k], d, 64);
                aO[g][k] += (unsigned)__shfl_xor((int)aO[g][k], d, 64);
            }
        }
        const int f   = lane & 15;                 // float4 index within row
        const int src = (lane & 0x30) | (f >> 2);  // owner lane (gg=0, s=f>>2)
        const int kk  = lane & 3;                  // word within owner's accs
        unsigned e = 0, o = 0;
        #pragma unroll
        for (int k = 0; k < 4; ++k) {
            const unsigned ek = (unsigned)__shfl((int)aE[g][k], src, 64);
            const unsigned ok = (unsigned)__shfl((int)aO[g][k], src, 64);
            if (kk == k) { e = ek; o = ok; }
        }
        const float cnt   = scnt[wave][g][v];
        const float qinv  = qs / fmaxf(cnt, 1.f);
        const float fbias = 128.f * cnt;   // remove uint8 offset once
        // cnt==0 => sums 0, bias 0 => out 0, matching the reference.
        vf4 r;
        r.x = ((float)(e & 0xffffu) - fbias) * qinv;   // dim 4f+0
        r.y = ((float)(o & 0xffffu) - fbias) * qinv;   // dim 4f+1
        r.z = ((float)(e >> 16)     - fbias) * qinv;   // dim 4f+2
        r.w = ((float)(o >> 16)     - fbias) * qinv;   // dim 4f+3
        const int v0 = (g * CHUNKS + chunk) * 4;
        if (v0 + v < N) {
            // flat float4 index = (v0+v)*16 + f = v0*16 + lane: one coalesced
            // 1KB NT store per wave per group.
            vf4* o4 = reinterpret_cast<vf4*>(out);
            __builtin_nontemporal_store(r, &o4[(long)v0 * 16 + lane]);
        }
    }
}

// ---------- Fallback (ws too small / N too large): R2-style fp32 kernel ----------
__global__ __launch_bounds__(256, 4)
void visit_fp32_kernel(const int* __restrict__ ids,
                       const float* __restrict__ emb,
                       float* __restrict__ out, int N) {
    const int tid  = threadIdx.x;
    const int lane = tid & 63;
    const int wave = tid >> 6;
    const int v    = blockIdx.x * 4 + wave;
    if (v >= N) return;

    int myid = -1;
    if (lane < LCODES) myid = ids[(long)v * LCODES + lane];
    const unsigned long long valid = __ballot(myid >= 0);
    const float cnt = (float)__popcll(valid);
    const int g = lane >> 3, s = lane & 7;
    const float4* __restrict__ emb4 = reinterpret_cast<const float4*>(emb);
    float4 accA = make_float4(0.f,0.f,0.f,0.f), accB = make_float4(0.f,0.f,0.f,0.f);
    #pragma unroll
    for (int it = 0; it < LCODES / 8; ++it) {
        const int id = __shfl(myid, it * 8 + g, 64);
        const float keep = (id >= 0) ? 1.f : 0.f;
        const unsigned base = ((unsigned)(id >= 0 ? id : 0)) << 4;
        float4 a = emb4[base + s], b = emb4[base + 8 + s];
        float ss = a.x*a.x + a.y*a.y + a.z*a.z + a.w*a.w
                 + b.x*b.x + b.y*b.y + b.z*b.z + b.w*b.w;
        ss += __shfl_xor(ss, 1, 64);
        ss += __shfl_xor(ss, 2, 64);
        ss += __shfl_xor(ss, 4, 64);
        float scale;
        if (__builtin_expect(__any(ss > 0.04f), 0)) {
            const float norm = fmaxf(sqrtf(ss), 1e-15f);
            const float arg  = fminf(norm, 1.f - 1e-7f);
            scale = 0.5f * logf((1.f + arg) / (1.f - arg)) / norm;
        } else {
            scale = 1.f + ss * (0.33333333333f + ss * (0.2f + ss * 0.14285714285f));
        }
        scale *= keep;
        accA.x += a.x*scale; accA.y += a.y*scale; accA.z += a.z*scale; accA.w += a.w*scale;
        accB.x += b.x*scale; accB.y += b.y*scale; accB.z += b.z*scale; accB.w += b.w*scale;
    }
    #pragma unroll
    for (int d = 8; d <= 32; d <<= 1) {
        accA.x += __shfl_xor(accA.x, d, 64); accA.y += __shfl_xor(accA.y, d, 64);
        accA.z += __shfl_xor(accA.z, d, 64); accA.w += __shfl_xor(accA.w, d, 64);
        accB.x += __shfl_xor(accB.x, d, 64); accB.y += __shfl_xor(accB.y, d, 64);
        accB.z += __shfl_xor(accB.z, d, 64); accB.w += __shfl_xor(accB.w, d, 64);
    }
    if (lane < 8) {
        const float inv = 1.f / fmaxf(cnt, 1.f);
        float4* o = reinterpret_cast<float4*>(out) + (long)v * (DIM / 4);
        o[2*s]   = make_float4(accA.x*inv, accA.y*inv, accA.z*inv, accA.w*inv);
        o[2*s+1] = make_float4(accB.x*inv, accB.y*inv, accB.z*inv, accB.w*inv);
    }
}

extern "C" void kernel_launch(void* const* d_in, const int* in_sizes, int n_in,
                              void* d_out, int out_size, void* d_ws, size_t ws_size,
                              hipStream_t stream) {
    const int*   ids = (const int*)d_in[0];
    const float* emb = (const float*)d_in[1];
    float*       out = (float*)d_out;

    const int N = in_sizes[0] / LCODES;   // 65536 visits
    const int C = in_sizes[1] / DIM;      // 100000 codes

    // ws layout: [0..4KB) bmax[1024] | [4KB..4KB+4) qs | [8KB..) int8 table (C+1 rows)
    const size_t tab_off = 8192;
    const size_t need = tab_off + (size_t)(C + 1) * DIM;   // ~6.4 MB

    // Persistent K3 covers up to CHUNKS*NG*4 = 65536 visits.
    if (ws_size >= need && N <= CHUNKS * NG * 4) {
        unsigned*      bmax = (unsigned*)d_ws;
        float*         qsp  = (float*)((char*)d_ws + 4096);
        unsigned char* tab  = (unsigned char*)d_ws + tab_off;

        const long n4 = (long)C * DIM / 4;
        hipLaunchKernelGGL(amax_kernel, dim3(1024), dim3(256), 0, stream,
                           emb, bmax, n4);
        const int blocksA = (C + 31) / 32;
        hipLaunchKernelGGL(build_i8_kernel, dim3(blocksA), dim3(256), 0, stream,
                           emb, bmax, tab, qsp, C);
        hipLaunchKernelGGL(visit_gather_i8p_kernel, dim3(K3_BLOCKS), dim3(256), 0,
                           stream, ids, tab, qsp, out, N, C);
    } else {
        const int blocks = (N + 3) / 4;
        hipLaunchKernelGGL(visit_fp32_kernel, dim3(blocks), dim3(256), 0, stream,
                           ids, emb, out, N);
    }
}

// Round 7
// 114.059 us; speedup vs baseline: 1.7858x; 1.7858x over previous
//
#include <hip/hip_runtime.h>

// VisitEncoder: out[v,:] = mean over valid codes j of logmap0(emb[ids[v,j]]), c=1.
//
// R16 = R15 resubmitted verbatim (R6's bench died on an infra error —
// "MI355X container failed twice" — before executing anything; no signal).
//
// R15: clean L2-capacity test — split K3 into TWO SEQUENTIAL LAUNCHES by
// dim-half. K3(hp=0) computes dims 0..31 for ALL visits from half-table 0
// (3.2MB); K3(hp=1) computes dims 32..63 from half-table 1. The kernel
// boundary is a hard chip-wide phase barrier: at any instant the gather
// working set is 3.2MB < 4MB per-XCD L2 — no XCD-mapping assumption (R13's
// flaw), no wave-phase mixing (R12's flaw), no register spill (R14's flaw:
// 96-gather unrolled body -> scratch-write-bound, 232MB writes).
//   * K2 half-table layout + K3 body reused from R13 (verified bit-identical,
//     absmax 1.144409e-05): 8 visits/wave, 2 lanes x 16B per 32B row, LDS id
//     stash stride 50, 16-shfl reduce, one float4 NT store per lane.
//   * per-kernel per-visit instruction cost is HALF of R11's, so the 2
//     launches together match R11's issue count; misses drop from ~150MB
//     L2-thrash to ~51MB compulsory (2 kernels x 8 XCDs x 3.2MB).
//   * ids read twice (NT both times: protects table's L2 residency; ~+2us).
// If this lands flat vs R11 (105.9), the capacity theory is dead (4th clean
// attempt) -> revert to R11, declare roofline.

#define LCODES 48
#define DIM 64

typedef float vf4 __attribute__((ext_vector_type(4)));

// ---------- K1: block-max of |emb| (positive-float bits are monotone) ----------
__global__ __launch_bounds__(256)
void amax_kernel(const float* __restrict__ emb, unsigned* __restrict__ bmax,
                 long n4) {
    const uint4* __restrict__ u4 = reinterpret_cast<const uint4*>(emb);
    const long T = (long)gridDim.x * 256;
    unsigned m = 0;
    for (long i = (long)blockIdx.x * 256 + threadIdx.x; i < n4; i += 2 * T) {
        const uint4 a = u4[i];
        m = max(m, a.x & 0x7fffffffu);
        m = max(m, a.y & 0x7fffffffu);
        m = max(m, a.z & 0x7fffffffu);
        m = max(m, a.w & 0x7fffffffu);
        if (i + T < n4) {
            const uint4 b = u4[i + T];
            m = max(m, b.x & 0x7fffffffu);
            m = max(m, b.y & 0x7fffffffu);
            m = max(m, b.z & 0x7fffffffu);
            m = max(m, b.w & 0x7fffffffu);
        }
    }
    #pragma unroll
    for (int d = 1; d <= 32; d <<= 1)
        m = max(m, (unsigned)__shfl_xor((int)m, d, 64));
    __shared__ unsigned sm[4];
    if ((threadIdx.x & 63) == 0) sm[threadIdx.x >> 6] = m;
    __syncthreads();
    if (threadIdx.x == 0)
        bmax[blockIdx.x] = max(max(sm[0], sm[1]), max(sm[2], sm[3]));
}

__device__ __forceinline__ float global_amax1024(const unsigned* __restrict__ bmax) {
    const int lane = threadIdx.x & 63;
    unsigned m = 0;
    #pragma unroll
    for (int k = 0; k < 16; ++k)
        m = max(m, bmax[lane + 64 * k]);
    #pragma unroll
    for (int d = 1; d <= 32; d <<= 1)
        m = max(m, (unsigned)__shfl_xor((int)m, d, 64));
    return __uint_as_float(m);
}

// ---------- K2: fp32 emb -> uint8 table, dim-half layout (rows C = zeros) ----
// tabh[h][row][32B]: h=0 -> dims 0..31, h=1 -> dims 32..63; row C = zeros.
__global__ __launch_bounds__(256)
void build_i8h_kernel(const float* __restrict__ emb,
                      const unsigned* __restrict__ bmax,
                      unsigned char* __restrict__ tab,
                      float* __restrict__ qsout, int C) {
    const float amax = global_amax1024(bmax);
    // 1.0006 bounds the artanh scale factor (ss <= 64*amax^2 -> scale <= 1.00056)
    const float qs   = amax * (1.0006f / 127.f);
    const float invq = (amax > 0.f) ? (127.f / (amax * 1.0006f)) : 0.f;
    if (blockIdx.x == 0 && threadIdx.x == 0) qsout[0] = qs;
    // zero rows (row C of each half) for padded ids
    if (blockIdx.x == 0 && threadIdx.x < 16) {
        const int h = threadIdx.x >> 3, wd = threadIdx.x & 7;
        reinterpret_cast<unsigned*>(tab)[((size_t)h * (C + 1) + C) * 8 + wd] = 0u;
    }

    const int tid  = threadIdx.x;
    const int lane = tid & 63;
    const int wave = tid >> 6;
    const int g = lane >> 3, s = lane & 7;      // s: dims 8s..8s+7
    const int r = blockIdx.x * 32 + wave * 8 + g;
    if (r >= C) return;

    const float4* __restrict__ emb4 = reinterpret_cast<const float4*>(emb);
    const float4 a = emb4[r * 16 + 2 * s];       // dims 8s..8s+3
    const float4 b = emb4[r * 16 + 2 * s + 1];   // dims 8s+4..8s+7

    float ss = a.x*a.x + a.y*a.y + a.z*a.z + a.w*a.w
             + b.x*b.x + b.y*b.y + b.z*b.z + b.w*b.w;
    ss += __shfl_xor(ss, 1, 64);
    ss += __shfl_xor(ss, 2, 64);
    ss += __shfl_xor(ss, 4, 64);

    float scale;
    if (__builtin_expect(ss > 0.04f, 0)) {
        // exact artanh path (never taken for this data; correctness guard)
        const float norm = fmaxf(sqrtf(ss), 1e-15f);
        const float arg  = fminf(norm, 1.f - 1e-7f);
        scale = 0.5f * logf((1.f + arg) / (1.f - arg)) / norm;
    } else {
        // artanh(z)/z = 1 + z^2/3 + z^4/5 + z^6/7,  z^2 = ss
        scale = 1.f + ss * (0.33333333333f + ss * (0.2f + ss * 0.14285714285f));
    }
    scale *= invq;   // fold quantization step into the tangent scale

    const float t[8] = { a.x*scale, a.y*scale, a.z*scale, a.w*scale,
                         b.x*scale, b.y*scale, b.z*scale, b.w*scale };
    unsigned u[8];
    #pragma unroll
    for (int k = 0; k < 8; ++k)
        u[k] = (unsigned)((int)rintf(t[k]) + 128);   // in [1,255]

    uint2 w;
    w.x = u[0] | (u[1] << 8) | (u[2] << 16) | (u[3] << 24);
    w.y = u[4] | (u[5] << 8) | (u[6] << 16) | (u[7] << 24);
    // half h = s>>2 holds dims [h*32, h*32+32) as a 32B row granule; this
    // lane's 8B sits at sub-slot (s&3).
    const int h = s >> 2;
    reinterpret_cast<uint2*>(tab)[((size_t)h * (C + 1) + r) * 4 + (s & 3)] = w;
}

// ---------- K3: one dim-half gather-mean, 8 visits/wave (launched twice) ----
__global__ __launch_bounds__(256)
void visit_gather_i8h2_kernel(const int* __restrict__ ids,
                              const unsigned char* __restrict__ tab,
                              const float* __restrict__ qsp,
                              float* __restrict__ out, int N, int C, int hp) {
    const float qs = qsp[0];          // uniform scalar load, hot line

    const int tid  = threadIdx.x;
    const int lane = tid & 63;
    const int wave = tid >> 6;
    const int v0   = (blockIdx.x * 4 + wave) * 8;   // this wave's 8 visits
    if (v0 >= N) return;

    __shared__ int   sids[4][8 * 50];   // stride 50: max 2-way bank alias (free)
    __shared__ float scnt[4][8];

    int m[8];
    #pragma unroll
    for (int r = 0; r < 8; ++r) m[r] = -1;
    if (lane < LCODES) {
        const long b = (long)v0 * LCODES + lane;
        #pragma unroll
        for (int r = 0; r < 8; ++r)
            if (v0 + r < N)
                m[r] = __builtin_nontemporal_load(&ids[b + (long)r * LCODES]);
        #pragma unroll
        for (int r = 0; r < 8; ++r) sids[wave][r * 50 + lane] = m[r];
    }
    #pragma unroll
    for (int r = 0; r < 8; ++r) {
        const float c = (float)__popcll(__ballot(m[r] >= 0));
        if (lane == 0) scnt[wave][r] = c;
    }

    const int v = lane >> 3;          // visit within the 8
    const int g = (lane >> 1) & 3;    // code-subgroup
    const int s = lane & 1;           // 16B slot within the 32B half-row
    const uint4* __restrict__ tab4 = reinterpret_cast<const uint4*>(tab);
    const unsigned hbase = (unsigned)(hp * (C + 1) * 2 + s);
    const int* __restrict__ slid = &sids[wave][v * 50 + g];

    // Packed accumulators: each u32 = two 16-bit sums (even/odd bytes).
    // Word k covers dims hp*32 + s*16 + 4k + {0..3}. 48*255 < 2^16: exact.
    unsigned aE[4] = {0,0,0,0}, aO[4] = {0,0,0,0};

    #pragma unroll
    for (int it = 0; it < LCODES / 4; ++it) {
        const int id = slid[4 * it];
        const unsigned row = (unsigned)(id >= 0 ? id : C);  // zero row if pad
        const uint4 w = tab4[hbase + (row << 1)];  // working set 3.2MB: L2-hit
        aE[0] +=  w.x       & 0x00ff00ffu;
        aO[0] += (w.x >> 8) & 0x00ff00ffu;
        aE[1] +=  w.y       & 0x00ff00ffu;
        aO[1] += (w.y >> 8) & 0x00ff00ffu;
        aE[2] +=  w.z       & 0x00ff00ffu;
        aO[2] += (w.z >> 8) & 0x00ff00ffu;
        aE[3] +=  w.w       & 0x00ff00ffu;
        aO[3] += (w.w >> 8) & 0x00ff00ffu;
    }

    // Combine the 4 g-subgroups (lane bits 1..2): 16 shfl total.
    #pragma unroll
    for (int d = 2; d <= 4; d <<= 1) {
        #pragma unroll
        for (int k = 0; k < 4; ++k) {
            aE[k] += (unsigned)__shfl_xor((int)aE[k], d, 64);
            aO[k] += (unsigned)__shfl_xor((int)aO[k], d, 64);
        }
    }

    // Epilogue: lane writes ONE float4 of its visit's dim-half.
    // f = lane&7 -> dims hp*32 + 4f + {0..3}; owner lane = (lane&0x38)|(f>>2)
    // (g=0, s=f>>2), word k = f&3.
    const int f   = lane & 7;
    const int src = (lane & 0x38) | (f >> 2);
    const int kk  = f & 3;
    unsigned e = 0, o = 0;
    #pragma unroll
    for (int k = 0; k < 4; ++k) {
        const unsigned ek = (unsigned)__shfl((int)aE[k], src, 64);
        const unsigned ok = (unsigned)__shfl((int)aO[k], src, 64);
        if (kk == k) { e = ek; o = ok; }
    }
    const float cnt   = scnt[wave][lane >> 3];
    const float qinv  = qs / fmaxf(cnt, 1.f);
    const float fbias = 128.f * cnt;   // remove uint8 offset once
    // cnt==0 => sums 0, bias 0 => out 0, matching the reference.
    vf4 r;
    r.x = ((float)(e & 0xffffu) - fbias) * qinv;   // dim hp*32+4f+0
    r.y = ((float)(o & 0xffffu) - fbias) * qinv;   // dim hp*32+4f+1
    r.z = ((float)(e >> 16)     - fbias) * qinv;   // dim hp*32+4f+2
    r.w = ((float)(o >> 16)     - fbias) * qinv;   // dim hp*32+4f+3
    const int vw = v0 + (lane >> 3);
    if (vw < N) {
        vf4* o4 = reinterpret_cast<vf4*>(out);
        __builtin_nontemporal_store(r, &o4[(long)vw * 16 + hp * 8 + f]);
    }
}

// ---------- Fallback (ws too small): R2-style all-fp32 kernel ----------
__global__ __launch_bounds__(256, 4)
void visit_fp32_kernel(const int* __restrict__ ids,
                       const float* __restrict__ emb,
                       float* __restrict__ out, int N) {
    const int tid  = threadIdx.x;
    const int lane = tid & 63;
    const int wave = tid >> 6;
    const int v    = blockIdx.x * 4 + wave;
    if (v >= N) return;

    int myid = -1;
    if (lane < LCODES) myid = ids[(long)v * LCODES + lane];
    const unsigned long long valid = __ballot(myid >= 0);
    const float cnt = (float)__popcll(valid);
    const int g = lane >> 3, s = lane & 7;
    const float4* __restrict__ emb4 = reinterpret_cast<const float4*>(emb);
    float4 accA = make_float4(0.f,0.f,0.f,0.f), accB = make_float4(0.f,0.f,0.f,0.f);
    #pragma unroll
    for (int it = 0; it < LCODES / 8; ++it) {
        const int id = __shfl(myid, it * 8 + g, 64);
        const float keep = (id >= 0) ? 1.f : 0.f;
        const unsigned base = ((unsigned)(id >= 0 ? id : 0)) << 4;
        float4 a = emb4[base + s], b = emb4[base + 8 + s];
        float ss = a.x*a.x + a.y*a.y + a.z*a.z + a.w*a.w
                 + b.x*b.x + b.y*b.y + b.z*b.z + b.w*b.w;
        ss += __shfl_xor(ss, 1, 64);
        ss += __shfl_xor(ss, 2, 64);
        ss += __shfl_xor(ss, 4, 64);
        float scale;
        if (__builtin_expect(__any(ss > 0.04f), 0)) {
            const float norm = fmaxf(sqrtf(ss), 1e-15f);
            const float arg  = fminf(norm, 1.f - 1e-7f);
            scale = 0.5f * logf((1.f + arg) / (1.f - arg)) / norm;
        } else {
            scale = 1.f + ss * (0.33333333333f + ss * (0.2f + ss * 0.14285714285f));
        }
        scale *= keep;
        accA.x += a.x*scale; accA.y += a.y*scale; accA.z += a.z*scale; accA.w += a.w*scale;
        accB.x += b.x*scale; accB.y += b.y*scale; accB.z += b.z*scale; accB.w += b.w*scale;
    }
    #pragma unroll
    for (int d = 8; d <= 32; d <<= 1) {
        accA.x += __shfl_xor(accA.x, d, 64); accA.y += __shfl_xor(accA.y, d, 64);
        accA.z += __shfl_xor(accA.z, d, 64); accA.w += __shfl_xor(accA.w, d, 64);
        accB.x += __shfl_xor(accB.x, d, 64); accB.y += __shfl_xor(accB.y, d, 64);
        accB.z += __shfl_xor(accB.z, d, 64); accB.w += __shfl_xor(accB.w, d, 64);
    }
    if (lane < 8) {
        const float inv = 1.f / fmaxf(cnt, 1.f);
        float4* o = reinterpret_cast<float4*>(out) + (long)v * (DIM / 4);
        o[2*s]   = make_float4(accA.x*inv, accA.y*inv, accA.z*inv, accA.w*inv);
        o[2*s+1] = make_float4(accB.x*inv, accB.y*inv, accB.z*inv, accB.w*inv);
    }
}

extern "C" void kernel_launch(void* const* d_in, const int* in_sizes, int n_in,
                              void* d_out, int out_size, void* d_ws, size_t ws_size,
                              hipStream_t stream) {
    const int*   ids = (const int*)d_in[0];
    const float* emb = (const float*)d_in[1];
    float*       out = (float*)d_out;

    const int N = in_sizes[0] / LCODES;   // 65536 visits
    const int C = in_sizes[1] / DIM;      // 100000 codes

    // ws layout: [0..4KB) bmax[1024] | [4KB..4KB+4) qs | [8KB..) dim-half
    // int8 table: 2 halves x (C+1) rows x 32B = (C+1)*64 bytes (~6.4 MB)
    const size_t tab_off = 8192;
    const size_t need = tab_off + (size_t)(C + 1) * DIM;

    if (ws_size >= need) {
        unsigned*      bmax = (unsigned*)d_ws;
        float*         qsp  = (float*)((char*)d_ws + 4096);
        unsigned char* tab  = (unsigned char*)d_ws + tab_off;

        const long n4 = (long)C * DIM / 4;
        hipLaunchKernelGGL(amax_kernel, dim3(1024), dim3(256), 0, stream,
                           emb, bmax, n4);
        const int blocksA = (C + 31) / 32;
        hipLaunchKernelGGL(build_i8h_kernel, dim3(blocksA), dim3(256), 0, stream,
                           emb, bmax, tab, qsp, C);
        // 8 visits/wave, 4 waves/block -> 32 visits/block; one launch per
        // dim-half: each launch's gather working set is 3.2MB (< 4MB L2),
        // enforced chip-wide by the kernel boundary.
        const int blocksB = (N + 31) / 32;
        hipLaunchKernelGGL(visit_gather_i8h2_kernel, dim3(blocksB), dim3(256), 0,
                           stream, ids, tab, qsp, out, N, C, 0);
        hipLaunchKernelGGL(visit_gather_i8h2_kernel, dim3(blocksB), dim3(256), 0,
                           stream, ids, tab, qsp, out, N, C, 1);
    } else {
        const int blocks = (N + 3) / 4;
        hipLaunchKernelGGL(visit_fp32_kernel, dim3(blocks), dim3(256), 0, stream,
                           ids, emb, out, N);
    }
}

// Round 8
// 106.892 us; speedup vs baseline: 1.9056x; 1.0670x over previous
//
#include <hip/hip_runtime.h>

// VisitEncoder: out[v,:] = mean over valid codes j of logmap0(emb[ids[v,j]]), c=1.
//
// R17 = R11 reverted verbatim (best measured: 105.87us, absmax 1.144409e-05).
// Post-R15 conclusion: the gather is at a random-access service-latency floor,
// not L2-capacity-bound. Four capacity/MLP attacks (R10 dwordx4-width, R12
// temporal windows, R13 XCD dim-split, R15 launch-boundary split) all landed
// flat-to-worse; R12's 2x instruction stream cost ~1us (not VALU-bound).
// Fixed budget: ~44us harness ws-poison fill + ~14us compulsory HBM traffic
// + 3 launches + gather service floor ~= 105us = R11's measurement.
//
// R11 structure: 3-kernel global-scale int8. K3: 4 visits/wave, 16 lanes/visit.
//   * 12 independent dwordx4 gathers in flight per wave.
//   * ids via per-wave LDS stash (1 ds_read/iter, <=2-way bank alias = free).
//   * reduce: 2 butterfly steps x 8 accs = 16 shfl/wave.
//   * epilogue: every lane writes ONE float4 -> a single fully-coalesced
//     1KB NT store per wave (flat index v0*16+lane).
//   * table gathers use normal loads (keep table L2-resident); NT only on
//     stream-once ids loads and out stores.
// Math: global qs = amax*1.0006/127 folded into tangent scale; exact
// packed-u16 sums (48*255 < 2^16); fbias/qinv epilogue. absmax 1.144409e-05.

#define LCODES 48
#define DIM 64

typedef float vf4 __attribute__((ext_vector_type(4)));

// ---------- K1: block-max of |emb| (positive-float bits are monotone) ----------
__global__ __launch_bounds__(256)
void amax_kernel(const float* __restrict__ emb, unsigned* __restrict__ bmax,
                 long n4) {
    const uint4* __restrict__ u4 = reinterpret_cast<const uint4*>(emb);
    const long T = (long)gridDim.x * 256;
    unsigned m = 0;
    for (long i = (long)blockIdx.x * 256 + threadIdx.x; i < n4; i += 2 * T) {
        const uint4 a = u4[i];
        m = max(m, a.x & 0x7fffffffu);
        m = max(m, a.y & 0x7fffffffu);
        m = max(m, a.z & 0x7fffffffu);
        m = max(m, a.w & 0x7fffffffu);
        if (i + T < n4) {
            const uint4 b = u4[i + T];
            m = max(m, b.x & 0x7fffffffu);
            m = max(m, b.y & 0x7fffffffu);
            m = max(m, b.z & 0x7fffffffu);
            m = max(m, b.w & 0x7fffffffu);
        }
    }
    #pragma unroll
    for (int d = 1; d <= 32; d <<= 1)
        m = max(m, (unsigned)__shfl_xor((int)m, d, 64));
    __shared__ unsigned sm[4];
    if ((threadIdx.x & 63) == 0) sm[threadIdx.x >> 6] = m;
    __syncthreads();
    if (threadIdx.x == 0)
        bmax[blockIdx.x] = max(max(sm[0], sm[1]), max(sm[2], sm[3]));
}

__device__ __forceinline__ float global_amax1024(const unsigned* __restrict__ bmax) {
    const int lane = threadIdx.x & 63;
    unsigned m = 0;
    #pragma unroll
    for (int k = 0; k < 16; ++k)
        m = max(m, bmax[lane + 64 * k]);
    #pragma unroll
    for (int d = 1; d <= 32; d <<= 1)
        m = max(m, (unsigned)__shfl_xor((int)m, d, 64));
    return __uint_as_float(m);
}

// ---------- K2: fp32 emb -> uint8 table (C+1 rows, row C = zeros) ----------
__global__ __launch_bounds__(256)
void build_i8_kernel(const float* __restrict__ emb,
                     const unsigned* __restrict__ bmax,
                     unsigned char* __restrict__ tab,
                     float* __restrict__ qsout, int C) {
    const float amax = global_amax1024(bmax);
    // 1.0006 bounds the artanh scale factor (ss <= 64*amax^2 -> scale <= 1.00056)
    const float qs   = amax * (1.0006f / 127.f);
    const float invq = (amax > 0.f) ? (127.f / (amax * 1.0006f)) : 0.f;
    if (blockIdx.x == 0 && threadIdx.x == 0) qsout[0] = qs;
    // zero-row for padded ids (gathers of id<0 land here)
    if (blockIdx.x == 0 && threadIdx.x < 16)
        reinterpret_cast<unsigned*>(tab + (size_t)C * DIM)[threadIdx.x] = 0u;

    const int tid  = threadIdx.x;
    const int lane = tid & 63;
    const int wave = tid >> 6;
    const int g = lane >> 3, s = lane & 7;
    const int r = blockIdx.x * 32 + wave * 8 + g;
    if (r >= C) return;

    const float4* __restrict__ emb4 = reinterpret_cast<const float4*>(emb);
    const float4 a = emb4[r * 16 + 2 * s];       // dims 8s..8s+3
    const float4 b = emb4[r * 16 + 2 * s + 1];   // dims 8s+4..8s+7

    float ss = a.x*a.x + a.y*a.y + a.z*a.z + a.w*a.w
             + b.x*b.x + b.y*b.y + b.z*b.z + b.w*b.w;
    ss += __shfl_xor(ss, 1, 64);
    ss += __shfl_xor(ss, 2, 64);
    ss += __shfl_xor(ss, 4, 64);

    float scale;
    if (__builtin_expect(ss > 0.04f, 0)) {
        // exact artanh path (never taken for this data; correctness guard)
        const float norm = fmaxf(sqrtf(ss), 1e-15f);
        const float arg  = fminf(norm, 1.f - 1e-7f);
        scale = 0.5f * logf((1.f + arg) / (1.f - arg)) / norm;
    } else {
        // artanh(z)/z = 1 + z^2/3 + z^4/5 + z^6/7,  z^2 = ss
        scale = 1.f + ss * (0.33333333333f + ss * (0.2f + ss * 0.14285714285f));
    }
    scale *= invq;   // fold quantization step into the tangent scale

    const float t[8] = { a.x*scale, a.y*scale, a.z*scale, a.w*scale,
                         b.x*scale, b.y*scale, b.z*scale, b.w*scale };
    unsigned u[8];
    #pragma unroll
    for (int k = 0; k < 8; ++k)
        u[k] = (unsigned)((int)rintf(t[k]) + 128);   // in [1,255]

    uint2 w;
    w.x = u[0] | (u[1] << 8) | (u[2] << 16) | (u[3] << 24);
    w.y = u[4] | (u[5] << 8) | (u[6] << 16) | (u[7] << 24);
    reinterpret_cast<uint2*>(tab)[r * 8 + s] = w;   // 64B/row, coalesced
}

// ---------- K3: gather-mean, 4 visits per wave, 16 lanes per visit ----------
__global__ __launch_bounds__(256)
void visit_gather_i8q_kernel(const int* __restrict__ ids,
                             const unsigned char* __restrict__ tab,
                             const float* __restrict__ qsp,
                             float* __restrict__ out, int N, int C) {
    const float qs = qsp[0];          // uniform scalar load, hot line

    const int tid  = threadIdx.x;
    const int lane = tid & 63;
    const int wave = tid >> 6;
    const int v0   = (blockIdx.x * 4 + wave) * 4;   // this wave's visit quad
    if (v0 >= N) return;

    __shared__ int sids[4][4 * LCODES];   // [wave][visit*48 + j], 3KB/block

    // Load 4 visits' ids (lanes 0..47; invalid visits stay -1 -> zero row),
    // stash to LDS (same-wave producer/consumer: no barrier needed).
    int m0 = -1, m1 = -1, m2 = -1, m3 = -1;
    if (lane < LCODES) {
        const long b = (long)v0 * LCODES;
        m0 = __builtin_nontemporal_load(&ids[b + lane]);
        if (v0 + 1 < N) m1 = __builtin_nontemporal_load(&ids[b + LCODES + lane]);
        if (v0 + 2 < N) m2 = __builtin_nontemporal_load(&ids[b + 2 * LCODES + lane]);
        if (v0 + 3 < N) m3 = __builtin_nontemporal_load(&ids[b + 3 * LCODES + lane]);
        sids[wave][lane]              = m0;
        sids[wave][LCODES + lane]     = m1;
        sids[wave][2 * LCODES + lane] = m2;
        sids[wave][3 * LCODES + lane] = m3;
    }
    const float cnt0 = (float)__popcll(__ballot(m0 >= 0));
    const float cnt1 = (float)__popcll(__ballot(m1 >= 0));
    const float cnt2 = (float)__popcll(__ballot(m2 >= 0));
    const float cnt3 = (float)__popcll(__ballot(m3 >= 0));

    const int v = lane >> 4;          // visit within quad
    const int g = (lane >> 2) & 3;    // code-subgroup within iteration
    const int s = lane & 3;           // uint4 slot = dims [16s..16s+15]
    const uint4* __restrict__ tab4 = reinterpret_cast<const uint4*>(tab);
    const int* __restrict__ slid = &sids[wave][v * LCODES + g];

    // Packed accumulators: each u32 = two 16-bit sums (even/odd bytes).
    // aE[k]/aO[k] cover dims 16s+4k+{0,2} / {1,3}. Max 48*255 < 2^16: exact.
    unsigned aE[4] = {0,0,0,0}, aO[4] = {0,0,0,0};

    #pragma unroll
    for (int it = 0; it < LCODES / 4; ++it) {
        const int id = slid[4 * it];                       // <=2-way bank alias: free
        const unsigned base = ((unsigned)(id >= 0 ? id : C)) << 2;
        const uint4 w = tab4[base + s];   // 12 independent gathers in flight
        aE[0] +=  w.x       & 0x00ff00ffu;
        aO[0] += (w.x >> 8) & 0x00ff00ffu;
        aE[1] +=  w.y       & 0x00ff00ffu;
        aO[1] += (w.y >> 8) & 0x00ff00ffu;
        aE[2] +=  w.z       & 0x00ff00ffu;
        aO[2] += (w.z >> 8) & 0x00ff00ffu;
        aE[3] +=  w.w       & 0x00ff00ffu;
        aO[3] += (w.w >> 8) & 0x00ff00ffu;
    }

    // Combine the 4 g-subgroups (lane bits 2..3). After this, every lane
    // holds the full sums for (its visit v, its slot s).
    #pragma unroll
    for (int d = 4; d <= 8; d <<= 1) {
        #pragma unroll
        for (int k = 0; k < 4; ++k) {
            aE[k] += (unsigned)__shfl_xor((int)aE[k], d, 64);
            aO[k] += (unsigned)__shfl_xor((int)aO[k], d, 64);
        }
    }

    // Epilogue: lane writes ONE float4. f = lane&15 -> dims 4f..4f+3 of its
    // visit; owner slot s*=f>>2 lives in lane (lane&0x30)|(f>>2), word k*=f&3.
    const int f   = lane & 15;
    const int src = (lane & 0x30) | (f >> 2);
    const int kk  = lane & 3;
    unsigned e = 0, o = 0;
    #pragma unroll
    for (int k = 0; k < 4; ++k) {
        const unsigned ek = (unsigned)__shfl((int)aE[k], src, 64);
        const unsigned ok = (unsigned)__shfl((int)aO[k], src, 64);
        if (kk == k) { e = ek; o = ok; }
    }
    const float cnt = (v == 0) ? cnt0 : (v == 1) ? cnt1 : (v == 2) ? cnt2 : cnt3;
    const float qinv  = qs / fmaxf(cnt, 1.f);
    const float fbias = 128.f * cnt;   // remove uint8 offset once
    // cnt==0 => sums 0, bias 0 => out 0, matching the reference.
    vf4 r;
    r.x = ((float)(e  & 0xffffu) - fbias) * qinv;   // dim 4f+0
    r.y = ((float)(o  & 0xffffu) - fbias) * qinv;   // dim 4f+1
    r.z = ((float)(e  >> 16)     - fbias) * qinv;   // dim 4f+2
    r.w = ((float)(o  >> 16)     - fbias) * qinv;   // dim 4f+3
    if (v0 + v < N) {
        // flat float4 index = (v0+v)*16 + f = v0*16 + lane: one coalesced
        // 1KB NT store per wave.
        vf4* o4 = reinterpret_cast<vf4*>(out);
        __builtin_nontemporal_store(r, &o4[(long)v0 * 16 + lane]);
    }
}

// ---------- Fallback (ws too small): R2-style all-fp32 kernel ----------
__global__ __launch_bounds__(256, 4)
void visit_fp32_kernel(const int* __restrict__ ids,
                       const float* __restrict__ emb,
                       float* __restrict__ out, int N) {
    const int tid  = threadIdx.x;
    const int lane = tid & 63;
    const int wave = tid >> 6;
    const int v    = blockIdx.x * 4 + wave;
    if (v >= N) return;

    int myid = -1;
    if (lane < LCODES) myid = ids[(long)v * LCODES + lane];
    const unsigned long long valid = __ballot(myid >= 0);
    const float cnt = (float)__popcll(valid);
    const int g = lane >> 3, s = lane & 7;
    const float4* __restrict__ emb4 = reinterpret_cast<const float4*>(emb);
    float4 accA = make_float4(0.f,0.f,0.f,0.f), accB = make_float4(0.f,0.f,0.f,0.f);
    #pragma unroll
    for (int it = 0; it < LCODES / 8; ++it) {
        const int id = __shfl(myid, it * 8 + g, 64);
        const float keep = (id >= 0) ? 1.f : 0.f;
        const unsigned base = ((unsigned)(id >= 0 ? id : 0)) << 4;
        float4 a = emb4[base + s], b = emb4[base + 8 + s];
        float ss = a.x*a.x + a.y*a.y + a.z*a.z + a.w*a.w
                 + b.x*b.x + b.y*b.y + b.z*b.z + b.w*b.w;
        ss += __shfl_xor(ss, 1, 64);
        ss += __shfl_xor(ss, 2, 64);
        ss += __shfl_xor(ss, 4, 64);
        float scale;
        if (__builtin_expect(__any(ss > 0.04f), 0)) {
            const float norm = fmaxf(sqrtf(ss), 1e-15f);
            const float arg  = fminf(norm, 1.f - 1e-7f);
            scale = 0.5f * logf((1.f + arg) / (1.f - arg)) / norm;
        } else {
            scale = 1.f + ss * (0.33333333333f + ss * (0.2f + ss * 0.14285714285f));
        }
        scale *= keep;
        accA.x += a.x*scale; accA.y += a.y*scale; accA.z += a.z*scale; accA.w += a.w*scale;
        accB.x += b.x*scale; accB.y += b.y*scale; accB.z += b.z*scale; accB.w += b.w*scale;
    }
    #pragma unroll
    for (int d = 8; d <= 32; d <<= 1) {
        accA.x += __shfl_xor(accA.x, d, 64); accA.y += __shfl_xor(accA.y, d, 64);
        accA.z += __shfl_xor(accA.z, d, 64); accA.w += __shfl_xor(accA.w, d, 64);
        accB.x += __shfl_xor(accB.x, d, 64); accB.y += __shfl_xor(accB.y, d, 64);
        accB.z += __shfl_xor(accB.z, d, 64); accB.w += __shfl_xor(accB.w, d, 64);
    }
    if (lane < 8) {
        const float inv = 1.f / fmaxf(cnt, 1.f);
        float4* o = reinterpret_cast<float4*>(out) + (long)v * (DIM / 4);
        o[2*s]   = make_float4(accA.x*inv, accA.y*inv, accA.z*inv, accA.w*inv);
        o[2*s+1] = make_float4(accB.x*inv, accB.y*inv, accB.z*inv, accB.w*inv);
    }
}

extern "C" void kernel_launch(void* const* d_in, const int* in_sizes, int n_in,
                              void* d_out, int out_size, void* d_ws, size_t ws_size,
                              hipStream_t stream) {
    const int*   ids = (const int*)d_in[0];
    const float* emb = (const float*)d_in[1];
    float*       out = (float*)d_out;

    const int N = in_sizes[0] / LCODES;   // 65536 visits
    const int C = in_sizes[1] / DIM;      // 100000 codes

    // ws layout: [0..4KB) bmax[1024] | [4KB..4KB+4) qs | [8KB..) int8 table (C+1 rows)
    const size_t tab_off = 8192;
    const size_t need = tab_off + (size_t)(C + 1) * DIM;   // ~6.4 MB

    if (ws_size >= need) {
        unsigned*      bmax = (unsigned*)d_ws;
        float*         qsp  = (float*)((char*)d_ws + 4096);
        unsigned char* tab  = (unsigned char*)d_ws + tab_off;

        const long n4 = (long)C * DIM / 4;
        hipLaunchKernelGGL(amax_kernel, dim3(1024), dim3(256), 0, stream,
                           emb, bmax, n4);
        const int blocksA = (C + 31) / 32;
        hipLaunchKernelGGL(build_i8_kernel, dim3(blocksA), dim3(256), 0, stream,
                           emb, bmax, tab, qsp, C);
        // 4 visits per wave, 4 waves per block -> 16 visits per block
        const int blocksB = (N + 15) / 16;
        hipLaunchKernelGGL(visit_gather_i8q_kernel, dim3(blocksB), dim3(256), 0,
                           stream, ids, tab, qsp, out, N, C);
    } else {
        const int blocks = (N + 3) / 4;
        hipLaunchKernelGGL(visit_fp32_kernel, dim3(blocks), dim3(256), 0, stream,
                           ids, emb, out, N);
    }
}